// Round 1
// 466.156 us; speedup vs baseline: 1.2021x; 1.2021x over previous
//
#include <hip/hip_runtime.h>

// SparseSpikingConv2D — Round 7: move the conv from the fp32 VALU pipe to the
// MFMA pipe via fp16 hi/lo split-precision implicit GEMM.
// R6 post-mortem: convA = 396 us, MfmaUtil 0, VALUBusy 42%; fp32-VALU floor is
// ~123 us (19.3 GFLOP @ 157 TF) -> the vector pipe is a dead end. CDNA4 has no
// fp32 MFMA, but x = xh + xl, w = wh + wl in fp16 (3 products xh*wh + xh*wl +
// xl*wh, fp32 MFMA accum) reproduces fp32 to ~1e-5 in the conv (~1.4e-6 in
// mthr, 70x inside the EPSB=2e-4 fixup band). MFMA floor ~28 us; HBM ~37 us.
// Existing exact-fp64 pass B handles threshold borderlines unchanged.

typedef _Float16 half8 __attribute__((ext_vector_type(8)));
typedef float f32x4 __attribute__((ext_vector_type(4)));

constexpr int CIc = 64, COc = 128, HHc = 64, WWc = 64, NBc = 32;
constexpr float EPSB = 2e-4f;        // borderline band on mthr
constexpr unsigned CAPc = 1u << 18;  // fixup list capacity (~13K observed)

// workspace layout (bytes)
constexpr size_t O_CNT   = 0;                    // 1 uint (padded 16)
constexpr size_t O_NORMD = 16;                   // 128 double
constexpr size_t O_RNORM = O_NORMD + 1024;       // 128 float
constexpr size_t O_WDT   = O_RNORM + 512;        // [co][t][ci] double = 589824 B
constexpr size_t O_WHI   = O_WDT + 589824;       // [t][co][ci] fp16 hi = 147456 B
constexpr size_t O_WLO   = O_WHI + 147456;       // [t][co][ci] fp16 lo = 147456 B
constexpr size_t O_LIST  = O_WLO + 147456;       // CAPc uint
constexpr size_t WS_NEED = O_LIST + (size_t)CAPc * 4;   // ~1.85 MB (< old 4.8 MB)

// Fused prep: blocks 0..127 -> norm (co=bx, 64-lane fp64 butterfly);
// blocks 128..415 -> wdT (fp64, for fixB) + whi/wlo (fp16 split, for convM).
__global__ void prep_kernel(const float* __restrict__ w, double* __restrict__ normd,
                            float* __restrict__ rnormf, double* __restrict__ wdT,
                            _Float16* __restrict__ whi, _Float16* __restrict__ wlo,
                            unsigned* __restrict__ counter) {
    const int bx = blockIdx.x;
    if (bx < 128) {
        const int co = bx, lane = threadIdx.x & 63;
        if (threadIdx.x >= 64) return;
        double s = 0.0;
        #pragma unroll
        for (int k = 0; k < 9; ++k) {
            const double v = (double)w[(k * 64 + lane) * COc + co];
            s = fma(v, v, s);
        }
        #pragma unroll
        for (int off = 32; off; off >>= 1) s += __shfl_xor(s, off);
        if (lane == 0) {
            s += 1e-8;
            normd[co]  = s;
            rnormf[co] = (float)(1.0 / s);
            if (co == 0) counter[0] = 0u;
        }
    } else {
        const int i = (bx - 128) * 256 + threadIdx.x;  // over 73728
        if (i >= 9 * CIc * COc) return;
        const int ci = i & 63, t = (i >> 6) % 9, co = i / (9 * 64);
        const float v = w[(t * CIc + ci) * COc + co];
        wdT[i] = (double)v;                            // wdT[co][t][ci]
        if (whi) {
            const int i2 = (t * COc + co) * CIc + ci;  // [t][co][ci]
            const _Float16 h = (_Float16)v;
            whi[i2] = h;
            wlo[i2] = (_Float16)(v - (float)h);
        }
    }
}

// ---- Pass A (MFMA): fp16-split implicit GEMM conv + LIF + spike + flagging ----
// Block = 256 thr = 4 waves; one (n, output-row y) per block.
// A = weights (M=cout), B = x (N=pixels), mfma_f32_16x16x32_f16.
//   A-frag: lane&15 = co_local, k = ci = (lane>>4)*8+j  (global load, L2-hot)
//   B-frag: lane&15 = px_local, k = ci                 (ds_read_b128, swizzled)
//   D: row = co = (lane>>4)*4+r, col = px = lane&15    (m89-verified layout)
// Wave w owns couts [w*32, w*32+32) x all 64 px: acc = 2x4 frags = 32 VGPR.
// LDS: x rows y-1..y+1, hi+lo fp16, [row][px+1][ci] (ci contiguous), XOR-swizzle
// byte ^= (px1&7)<<4 on BOTH write and read (T2; rule #21 both-sides).
__global__ __launch_bounds__(256, 2) void convM(
    const float* __restrict__ x,       // [32,64,64,64]
    const float* __restrict__ mem,     // [32,128,64,64]
    const _Float16* __restrict__ whi,  // [9,128,64]
    const _Float16* __restrict__ wlo,  // [9,128,64]
    const float* __restrict__ beta_p,
    const float* __restrict__ bias,
    const float* __restrict__ rnormf,
    float* __restrict__ out_spk, float* __restrict__ out_mem,
    unsigned* __restrict__ counter, unsigned* __restrict__ list)
{
    __shared__ _Float16 xs[2][3 * 66 * 64];   // [hi/lo][row*66+px1][ci] = 49.5 KB

    const int tid = threadIdx.x;
    const int y = blockIdx.x, n = blockIdx.y;

    // ---- stage: 3 rows x 8 ci-groups x 66 px1 (px1=0..65 <-> px=-1..64) ----
    for (int i = tid; i < 3 * 8 * 66; i += 256) {
        const int px1 = i % 66;
        const int q   = i / 66;
        const int cig = q & 7, row = q >> 3;
        const int yy  = y + row - 1;
        const bool valid = (px1 >= 1) && (px1 <= 64) && (yy >= 0) && (yy < HHc);
        const float* xp = x + (((size_t)n * CIc + cig * 8) * HHc + (valid ? yy : 0)) * WWc
                            + (valid ? (px1 - 1) : 0);
        half8 hv, lv;
        #pragma unroll
        for (int j = 0; j < 8; ++j) {
            const float v = valid ? xp[j * (HHc * WWc)] : 0.0f;
            const _Float16 h = (_Float16)v;
            hv[j] = h;
            lv[j] = (_Float16)(v - (float)h);
        }
        const unsigned off = (unsigned)(row * 66 + px1) * 128
                           + (((unsigned)cig * 16) ^ (((unsigned)px1 & 7) << 4));
        *(half8*)((char*)(&xs[0][0]) + off) = hv;
        *(half8*)((char*)(&xs[1][0]) + off) = lv;
    }
    __syncthreads();

    // ---- compute ----
    const int lane   = tid & 63;
    const int wv     = tid >> 6;          // 0..3 -> cout range
    const int co0    = wv * 32;
    const int lanelo = lane & 15;
    const unsigned kg2 = (unsigned)((lane >> 4) * 16);  // byte offset of k-group

    f32x4 acc[2][4];
    #pragma unroll
    for (int a = 0; a < 2; ++a)
        #pragma unroll
        for (int b = 0; b < 4; ++b) acc[a][b] = f32x4{0.f, 0.f, 0.f, 0.f};

    const _Float16* wh_l = whi + (size_t)(co0 + lanelo) * 64 + (lane >> 4) * 8;
    const _Float16* wl_l = wlo + (size_t)(co0 + lanelo) * 64 + (lane >> 4) * 8;
    const char* xs0 = (const char*)(&xs[0][0]);
    const char* xs1 = (const char*)(&xs[1][0]);

    #pragma unroll 3
    for (int t = 0; t < 9; ++t) {
        const int dy = t / 3, dx = t % 3;
        unsigned rb[4], sz[4];
        #pragma unroll
        for (int pf = 0; pf < 4; ++pf) {
            const int px1 = pf * 16 + lanelo + dx;      // 0..65, in bounds
            rb[pf] = (unsigned)(dy * 66 + px1) * 128;   // 128B per px row
            sz[pf] = ((unsigned)px1 & 7) << 4;          // T2 XOR swizzle
        }
        #pragma unroll
        for (int cs = 0; cs < 2; ++cs) {                // ci0 = cs*32, K=32/step
            const half8 ah0 = *(const half8*)(wh_l + t * 8192 + 0 * 1024 + cs * 32);
            const half8 ah1 = *(const half8*)(wh_l + t * 8192 + 1 * 1024 + cs * 32);
            const half8 al0 = *(const half8*)(wl_l + t * 8192 + 0 * 1024 + cs * 32);
            const half8 al1 = *(const half8*)(wl_l + t * 8192 + 1 * 1024 + cs * 32);
            #pragma unroll
            for (int pf = 0; pf < 4; ++pf) {
                const unsigned ob = rb[pf] + (((unsigned)cs * 64 + kg2) ^ sz[pf]);
                const half8 bh = *(const half8*)(xs0 + ob);
                const half8 bl = *(const half8*)(xs1 + ob);
                acc[0][pf] = __builtin_amdgcn_mfma_f32_16x16x32_f16(ah0, bh, acc[0][pf], 0, 0, 0);
                acc[0][pf] = __builtin_amdgcn_mfma_f32_16x16x32_f16(ah0, bl, acc[0][pf], 0, 0, 0);
                acc[0][pf] = __builtin_amdgcn_mfma_f32_16x16x32_f16(al0, bh, acc[0][pf], 0, 0, 0);
                acc[1][pf] = __builtin_amdgcn_mfma_f32_16x16x32_f16(ah1, bh, acc[1][pf], 0, 0, 0);
                acc[1][pf] = __builtin_amdgcn_mfma_f32_16x16x32_f16(ah1, bl, acc[1][pf], 0, 0, 0);
                acc[1][pf] = __builtin_amdgcn_mfma_f32_16x16x32_f16(al1, bh, acc[1][pf], 0, 0, 0);
            }
        }
    }

    // ---- epilogue: LIF + multi-threshold spike + borderline flagging ----
    const float beta = beta_p[0];
    const float omb  = 1.0f - beta;

    #pragma unroll
    for (int cf = 0; cf < 2; ++cf) {
        #pragma unroll
        for (int pf = 0; pf < 4; ++pf) {
            const int px = pf * 16 + lanelo;
            #pragma unroll
            for (int r = 0; r < 4; ++r) {
                const int co = co0 + cf * 16 + (lane >> 4) * 4 + r;
                const size_t idx = (((size_t)n * COc + co) * HHc + y) * WWc + px;
                const float nm   = fmaf(mem[idx], beta, acc[cf][pf][r] * omb);
                const float mthr = fmaf(nm, rnormf[co], -bias[co]);
                const int s = (mthr > 0.f) + (mthr > 1.f) + (mthr > 2.f) + (mthr > 3.f);
                out_spk[idx] = (float)s;
                out_mem[idx] = (s > 0) ? 0.0f : nm;

                const bool fl = (fabsf(mthr) < EPSB) | (fabsf(mthr - 1.f) < EPSB) |
                                (fabsf(mthr - 2.f) < EPSB) | (fabsf(mthr - 3.f) < EPSB);
                const unsigned long long msk = __ballot(fl);
                if (msk) {
                    unsigned wb = 0;
                    if (lane == 0) wb = atomicAdd(counter, (unsigned)__popcll(msk));
                    wb = __shfl(wb, 0);
                    if (fl) {
                        const unsigned pos =
                            wb + (unsigned)__popcll(msk & ((1ull << lane) - 1ull));
                        if (pos < CAPc) list[pos] = (unsigned)idx;
                    }
                }
            }
        }
    }
}

// ---- Pass B: exact fp64 recompute of flagged pixels (wave per pixel, lane=ci) ----
__global__ __launch_bounds__(256) void fixB(
    const float* __restrict__ x, const float* __restrict__ mem,
    const float* __restrict__ beta_p, const float* __restrict__ bias,
    const double* __restrict__ normd, const double* __restrict__ wdT,
    const unsigned* __restrict__ counter, const unsigned* __restrict__ list,
    float* __restrict__ out_spk, float* __restrict__ out_mem)
{
    const int lane  = threadIdx.x & 63;
    const int wave  = blockIdx.x * 4 + (threadIdx.x >> 6);
    const int nwave = gridDim.x * 4;
    const unsigned cnt = min(counter[0], CAPc);
    const double beta = (double)beta_p[0];
    const double omb  = 1.0 - beta;

    for (unsigned p = wave; p < cnt; p += nwave) {
        const unsigned idx = list[p];
        const int xp = idx & 63, yp = (idx >> 6) & 63;
        const int co = (idx >> 12) & 127, n = idx >> 19;

        const float*  xc = x + ((size_t)n * CIc + lane) * (HHc * WWc);
        const double* wt = wdT + (size_t)co * 9 * CIc + lane;

        double a = 0.0;
        #pragma unroll
        for (int t = 0; t < 9; ++t) {
            const int yy = yp + t / 3 - 1, xx = xp + t % 3 - 1;
            const bool v = ((unsigned)yy < 64u) && ((unsigned)xx < 64u);
            const int yyc = min(max(yy, 0), 63), xxc = min(max(xx, 0), 63);
            const double xv = v ? (double)xc[yyc * WWc + xxc] : 0.0;
            a = fma(xv, wt[t * CIc], a);
        }
        #pragma unroll
        for (int off = 32; off; off >>= 1) a += __shfl_xor(a, off);

        if (lane == 0) {
            const double nm   = (double)mem[idx] * beta + a * omb;
            const double mthr = nm / normd[co] - (double)bias[co];
            const int s = (mthr > 0.) + (mthr > 1.) + (mthr > 2.) + (mthr > 3.);
            out_spk[idx] = (float)s;
            out_mem[idx] = (s > 0) ? 0.0f : (float)nm;
        }
    }
}

// ---- Fallback (ws too small): all-fp64 direct conv ----
__global__ __launch_bounds__(256) void conv_fp64_fb(
    const float* __restrict__ x, const float* __restrict__ mem,
    const float* __restrict__ w, const float* __restrict__ beta_p,
    const float* __restrict__ bias, const double* __restrict__ normd,
    float* __restrict__ out_spk, float* __restrict__ out_mem)
{
    const int ix = threadIdx.x, iy = blockIdx.x * 4 + threadIdx.y;
    const int co0 = blockIdx.y * 8, n = blockIdx.z;
    bool valid[9]; int xoff[9];
    #pragma unroll
    for (int kh = 0; kh < 3; ++kh) {
        const int yy = iy + kh - 1;
        #pragma unroll
        for (int kw = 0; kw < 3; ++kw) {
            const int xx = ix + kw - 1, t = kh * 3 + kw;
            valid[t] = ((unsigned)yy < 64u) && ((unsigned)xx < 64u);
            xoff[t]  = yy * WWc + xx;
        }
    }
    double acc[8];
    #pragma unroll
    for (int j = 0; j < 8; ++j) acc[j] = 0.0;
    const float* xb = x + (size_t)n * CIc * HHc * WWc;
    for (int ci = 0; ci < CIc; ++ci) {
        const float* xc = xb + (size_t)ci * HHc * WWc;
        #pragma unroll
        for (int t = 0; t < 9; ++t) {
            const double xv = valid[t] ? (double)xc[xoff[t]] : 0.0;
            const float* wt = w + ((size_t)t * CIc + ci) * COc + co0;
            #pragma unroll
            for (int j = 0; j < 8; ++j) acc[j] = fma(xv, (double)wt[j], acc[j]);
        }
    }
    const double beta = (double)beta_p[0], omb = 1.0 - beta;
    const size_t base = (((size_t)n * COc + co0) * HHc + iy) * WWc + ix;
    #pragma unroll
    for (int j = 0; j < 8; ++j) {
        const size_t idx = base + (size_t)j * (HHc * WWc);
        const double nm   = (double)mem[idx] * beta + acc[j] * omb;
        const double mthr = nm / normd[co0 + j] - (double)bias[co0 + j];
        const int s = (mthr > 0.) + (mthr > 1.) + (mthr > 2.) + (mthr > 3.);
        out_spk[idx] = (float)s;
        out_mem[idx] = (s > 0) ? 0.0f : (float)nm;
    }
}

extern "C" void kernel_launch(void* const* d_in, const int* in_sizes, int n_in,
                              void* d_out, int out_size, void* d_ws, size_t ws_size,
                              hipStream_t stream) {
    const float* x      = (const float*)d_in[0];
    const float* mem    = (const float*)d_in[1];
    const float* w      = (const float*)d_in[2];
    const float* beta_p = (const float*)d_in[3];
    const float* bias   = (const float*)d_in[4];

    float* out_spk = (float*)d_out;
    float* out_mem = out_spk + (size_t)NBc * COc * HHc * WWc;

    char* ws = (char*)d_ws;
    unsigned* counter = (unsigned*)(ws + O_CNT);
    double*   normd   = (double*)(ws + O_NORMD);
    float*    rnormf  = (float*)(ws + O_RNORM);
    double*   wdT     = (double*)(ws + O_WDT);
    _Float16* whi     = (_Float16*)(ws + O_WHI);
    _Float16* wlo     = (_Float16*)(ws + O_WLO);
    unsigned* list    = (unsigned*)(ws + O_LIST);

    if (ws_size >= WS_NEED) {
        prep_kernel<<<128 + 288, 256, 0, stream>>>(w, normd, rnormf, wdT, whi, wlo,
                                                   counter);
        dim3 grdM(HHc, NBc, 1);            // 64 rows x 32 images = 2048 blocks
        convM<<<grdM, 256, 0, stream>>>(x, mem, whi, wlo, beta_p, bias, rnormf,
                                        out_spk, out_mem, counter, list);
        fixB<<<512, 256, 0, stream>>>(x, mem, beta_p, bias, normd, wdT,
                                      counter, list, out_spk, out_mem);
    } else {
        prep_kernel<<<128, 256, 0, stream>>>(w, normd, rnormf, wdT, nullptr, nullptr,
                                             counter);
        dim3 blk(WWc, 4, 1);
        dim3 grd(HHc / 4, COc / 8, NBc);
        conv_fp64_fb<<<grd, blk, 0, stream>>>(x, mem, w, beta_p, bias, normd,
                                              out_spk, out_mem);
    }
}